// Round 3
// baseline (114.081 us; speedup 1.0000x reference)
//
#include <hip/hip_runtime.h>

#define DIM 128          // x is (2,4,128,128,128) -> NC=8 volumes of 128^3
#define NCV 8

// Fused 2-level 3D Haar DWT, fp32 in / fp32 out.
// Per block: x-tile 8(D) x 8(H) x 64(W) at (nc, td*8, th*8, tw*64).
// Phase 1: 256 threads, each owns two w-adjacent 2x2x2 blocks -> level-1
//          butterfly; 7 high bands -> global (float2), LLL -> LDS (fp32).
// Phase 2: 64 threads, level-2 butterfly from LDS -> LL2 + 7 high bands.
__global__ __launch_bounds__(256)
void haar3d_fused(const float* __restrict__ x,
                  const float* __restrict__ h0,
                  const float* __restrict__ h1,
                  float* __restrict__ ll2,   // (NC, 32,32,32)
                  float* __restrict__ hi1,   // (NC, 7, 64,64,64)
                  float* __restrict__ hi2)   // (NC, 7, 32,32,32)
{
    __shared__ float2 lds[4 * 4 * 16];   // [sd][sh][sw2] -> (LLL siteA, LLL siteB)

    const int tw = blockIdx.x;        // 0..1
    const int th = blockIdx.y;        // 0..15
    const int td = blockIdx.z & 15;   // 0..15
    const int nc = blockIdx.z >> 4;   // 0..7

    const int tid = threadIdx.x;
    const int sw2 = tid & 15;         // 0..15 (pair of w-sites)
    const int sh  = (tid >> 4) & 3;   // 0..3
    const int sd  = tid >> 6;         // 0..3

    const float g00 = h0[0], g01 = h0[1];
    const float g10 = h1[0], g11 = h1[1];

    // ---------------- phase 1: level 1 ----------------
    const int gd = td * 8 + 2 * sd;
    const int gh = th * 8 + 2 * sh;
    const int gw = tw * 64 + 4 * sw2;

    const float* base = x + ((((long)nc * DIM + gd) * DIM + gh) * DIM + gw);

    float4 q[2][2];   // [d-offset i][h-offset j] : 4 consecutive w values
    q[0][0] = *reinterpret_cast<const float4*>(base);
    q[0][1] = *reinterpret_cast<const float4*>(base + DIM);
    q[1][0] = *reinterpret_cast<const float4*>(base + DIM * DIM);
    q[1][1] = *reinterpret_cast<const float4*>(base + DIM * DIM + DIM);

    // W stage: per row, per site s (A: x0,x1 | B: x2,x3)
    float Lw[2][2][2], Hw[2][2][2];   // [i][j][s]
#pragma unroll
    for (int i = 0; i < 2; ++i)
#pragma unroll
        for (int j = 0; j < 2; ++j) {
            const float4 v = q[i][j];
            Lw[i][j][0] = g00 * v.x + g01 * v.y;
            Hw[i][j][0] = g10 * v.x + g11 * v.y;
            Lw[i][j][1] = g00 * v.z + g01 * v.w;
            Hw[i][j][1] = g10 * v.z + g11 * v.w;
        }

    // H stage; names [w-band][h-band]
    float LL[2][2], LH[2][2], HL[2][2], HH[2][2];   // [i][s]
#pragma unroll
    for (int i = 0; i < 2; ++i)
#pragma unroll
        for (int s = 0; s < 2; ++s) {
            LL[i][s] = g00 * Lw[i][0][s] + g01 * Lw[i][1][s];
            LH[i][s] = g10 * Lw[i][0][s] + g11 * Lw[i][1][s];
            HL[i][s] = g00 * Hw[i][0][s] + g01 * Hw[i][1][s];
            HH[i][s] = g10 * Hw[i][0][s] + g11 * Hw[i][1][s];
        }

    // D stage; names [w-band][h-band][d-band]
    float LLL[2], LLH[2], LHL[2], LHH[2], HLL[2], HLH[2], HHL[2], HHH[2];
#pragma unroll
    for (int s = 0; s < 2; ++s) {
        LLL[s] = g00 * LL[0][s] + g01 * LL[1][s];
        LLH[s] = g10 * LL[0][s] + g11 * LL[1][s];
        LHL[s] = g00 * LH[0][s] + g01 * LH[1][s];
        LHH[s] = g10 * LH[0][s] + g11 * LH[1][s];
        HLL[s] = g00 * HL[0][s] + g01 * HL[1][s];
        HLH[s] = g10 * HL[0][s] + g11 * HL[1][s];
        HHL[s] = g00 * HH[0][s] + g01 * HH[1][s];
        HHH[s] = g10 * HH[0][s] + g11 * HH[1][s];
    }

    // level-1 site coords (pair base; sites are w1, w1+1)
    const int d1  = td * 4 + sd;
    const int h1c = th * 4 + sh;
    const int w1  = tw * 32 + 2 * sw2;   // even -> 8B-aligned float2 store

    // band order: b = bw*4 + bh*2 + bd; highs are b=1..7 -> plane b-1
    {
        const long S1 = 64L * 64 * 64;
        const long sp = ((long)d1 * 64 + h1c) * 64 + w1;
        float* hb = hi1 + (long)nc * 7 * S1 + sp;
        *reinterpret_cast<float2*>(hb + 0 * S1) = make_float2(LLH[0], LLH[1]);  // b=1
        *reinterpret_cast<float2*>(hb + 1 * S1) = make_float2(LHL[0], LHL[1]);  // b=2
        *reinterpret_cast<float2*>(hb + 2 * S1) = make_float2(LHH[0], LHH[1]);  // b=3
        *reinterpret_cast<float2*>(hb + 3 * S1) = make_float2(HLL[0], HLL[1]);  // b=4
        *reinterpret_cast<float2*>(hb + 4 * S1) = make_float2(HLH[0], HLH[1]);  // b=5
        *reinterpret_cast<float2*>(hb + 5 * S1) = make_float2(HHL[0], HHL[1]);  // b=6
        *reinterpret_cast<float2*>(hb + 6 * S1) = make_float2(HHH[0], HHH[1]);  // b=7
    }

    lds[(sd * 4 + sh) * 16 + sw2] = make_float2(LLL[0], LLL[1]);

    __syncthreads();

    // ---------------- phase 2: level 2 from LDS ----------------
    if (tid < 64) {
        const int zw = tid & 15;         // 0..15
        const int zh = (tid >> 4) & 1;   // 0..1
        const int zd = tid >> 5;         // 0..1

        float Lw2[2][2], Hw2[2][2];      // [i][j]
#pragma unroll
        for (int i = 0; i < 2; ++i)
#pragma unroll
            for (int j = 0; j < 2; ++j) {
                const float2 p = lds[((2 * zd + i) * 4 + (2 * zh + j)) * 16 + zw];
                Lw2[i][j] = g00 * p.x + g01 * p.y;
                Hw2[i][j] = g10 * p.x + g11 * p.y;
            }

        float LL2v[2], LH2[2], HL2[2], HH2[2];   // [i]
#pragma unroll
        for (int i = 0; i < 2; ++i) {
            LL2v[i] = g00 * Lw2[i][0] + g01 * Lw2[i][1];
            LH2[i]  = g10 * Lw2[i][0] + g11 * Lw2[i][1];
            HL2[i]  = g00 * Hw2[i][0] + g01 * Hw2[i][1];
            HH2[i]  = g10 * Hw2[i][0] + g11 * Hw2[i][1];
        }

        const float vLLL = g00 * LL2v[0] + g01 * LL2v[1];
        const float vLLH = g10 * LL2v[0] + g11 * LL2v[1];
        const float vLHL = g00 * LH2[0]  + g01 * LH2[1];
        const float vLHH = g10 * LH2[0]  + g11 * LH2[1];
        const float vHLL = g00 * HL2[0]  + g01 * HL2[1];
        const float vHLH = g10 * HL2[0]  + g11 * HL2[1];
        const float vHHL = g00 * HH2[0]  + g01 * HH2[1];
        const float vHHH = g10 * HH2[0]  + g11 * HH2[1];

        const int d2 = td * 2 + zd;
        const int h2 = th * 2 + zh;
        const int w2 = tw * 16 + zw;

        ll2[(((long)nc * 32 + d2) * 32 + h2) * 32 + w2] = vLLL;

        const long S2 = 32L * 32 * 32;
        const long sp2 = ((long)d2 * 32 + h2) * 32 + w2;
        float* hb2 = hi2 + (long)nc * 7 * S2 + sp2;
        hb2[0 * S2] = vLLH;
        hb2[1 * S2] = vLHL;
        hb2[2 * S2] = vLHH;
        hb2[3 * S2] = vHLL;
        hb2[4 * S2] = vHLH;
        hb2[5 * S2] = vHHL;
        hb2[6 * S2] = vHHH;
    }
}

extern "C" void kernel_launch(void* const* d_in, const int* in_sizes, int n_in,
                              void* d_out, int out_size, void* d_ws, size_t ws_size,
                              hipStream_t stream) {
    const float* x  = (const float*)d_in[0];
    const float* h0 = (const float*)d_in[1];
    const float* h1 = (const float*)d_in[2];
    float* out = (float*)d_out;

    const long LL2_SZ = (long)NCV * 32 * 32 * 32;        //   262,144
    const long H1_SZ  = (long)NCV * 7 * 64 * 64 * 64;    // 14,680,064
    float* ll2 = out;
    float* hi1 = out + LL2_SZ;
    float* hi2 = out + LL2_SZ + H1_SZ;

    // grid: x = tw (W/64 = 2), y = th (H/8 = 16), z = td (D/8=16) + 16*nc
    dim3 grid(2, 16, 16 * NCV);
    haar3d_fused<<<grid, 256, 0, stream>>>(x, h0, h1, ll2, hi1, hi2);
}